// Round 3
// baseline (209.973 us; speedup 1.0000x reference)
//
#include <hip/hip_runtime.h>

// ---------------- types / helpers ----------------
using bf16x8 = __attribute__((ext_vector_type(8))) short;
using f32x4  = __attribute__((ext_vector_type(4))) float;

static __device__ inline unsigned short f2bf(float f) {
  unsigned int u = __float_as_uint(f);
  u += 0x7fffu + ((u >> 16) & 1u);          // round-to-nearest-even
  return (unsigned short)(u >> 16);
}
static __device__ inline unsigned int pk2(float a, float b) {
  return (unsigned int)f2bf(a) | ((unsigned int)f2bf(b) << 16);
}

// butterfly reductions across the 16-lane DPP row (row_ror 1,2,4,8)
#define ROW16_MAX(x) { \
  { int _t = __builtin_amdgcn_update_dpp(0, __float_as_int(x), 0x121, 0xf, 0xf, true); x = fmaxf(x, __int_as_float(_t)); } \
  { int _t = __builtin_amdgcn_update_dpp(0, __float_as_int(x), 0x122, 0xf, 0xf, true); x = fmaxf(x, __int_as_float(_t)); } \
  { int _t = __builtin_amdgcn_update_dpp(0, __float_as_int(x), 0x124, 0xf, 0xf, true); x = fmaxf(x, __int_as_float(_t)); } \
  { int _t = __builtin_amdgcn_update_dpp(0, __float_as_int(x), 0x128, 0xf, 0xf, true); x = fmaxf(x, __int_as_float(_t)); } }
#define ROW16_SUM(x) { \
  { int _t = __builtin_amdgcn_update_dpp(0, __float_as_int(x), 0x121, 0xf, 0xf, true); x += __int_as_float(_t); } \
  { int _t = __builtin_amdgcn_update_dpp(0, __float_as_int(x), 0x122, 0xf, 0xf, true); x += __int_as_float(_t); } \
  { int _t = __builtin_amdgcn_update_dpp(0, __float_as_int(x), 0x124, 0xf, 0xf, true); x += __int_as_float(_t); } \
  { int _t = __builtin_amdgcn_update_dpp(0, __float_as_int(x), 0x128, 0xf, 0xf, true); x += __int_as_float(_t); } }

// ---------------- kernel 0: weight prep (transpose -> bf16) ----------------
__global__ __launch_bounds__(256) void prep_kernel(
    const float* __restrict__ Wq, const float* __restrict__ Wk, const float* __restrict__ Wv,
    const float* __restrict__ Wo, const float* __restrict__ bq, const float* __restrict__ bk,
    const float* __restrict__ bv,
    unsigned short* __restrict__ Wt, unsigned short* __restrict__ Wot, float* __restrict__ bqkv)
{
  int idx = blockIdx.x * 256 + threadIdx.x;
  if (idx < 192 * 1024) {
    int n = idx >> 10, k = idx & 1023;
    const float* W = (n < 64) ? Wq : (n < 128) ? Wk : Wv;
    Wt[idx] = f2bf(W[k * 64 + (n & 63)]);
  } else if (idx < 192 * 1024 + 1024 * 64) {
    int j = idx - 192 * 1024;
    int n = j >> 6, k = j & 63;
    Wot[j] = f2bf(Wo[k * 1024 + n]);
  } else if (idx < 192 * 1024 + 1024 * 64 + 192) {
    int n = idx - (192 * 1024 + 1024 * 64);
    bqkv[n] = (n < 64) ? bq[n] : (n < 128) ? bk[n - 64] : bv[n - 128];
  }
}

// ---------------- kernel 1: QKV projection (bf16 MFMA, pipelined) ----------------
// X [16384][1024] fp32, Wt [192][1024] bf16 -> qkv [16384][192] fp32
// BM=32, BN=192, BK=64; grid 512 (2 blocks/CU). Double-buffered LDS +
// register prefetch: ks+1's global loads are in flight across the barrier
// and the MFMA phase of ks (vmcnt consumed at the LDS write AFTER the MFMAs).
__global__ __launch_bounds__(256) void qkv_gemm(
    const float* __restrict__ X, const unsigned short* __restrict__ Wt,
    const float* __restrict__ bqkv, float* __restrict__ qkv)
{
  __shared__ __align__(16) unsigned short As[2][32 * 72];
  __shared__ __align__(16) unsigned short Bs[2][192 * 72];
  int t = threadIdx.x;
  int lane = t & 63, w = t >> 6;
  int m0 = blockIdx.x * 32;
  int mg = w & 1, ng = w >> 1;
  int col = lane & 15, quad = lane >> 4;
  f32x4 acc[6] = {};

  // staging coords
  int rowA = t >> 3, cA = t & 7;                 // A: 32 rows x 8 uint4-chunks
  int nB = t >> 3, cB = t & 7;                   // B: rows nB+32r, chunk cB
  const float* srcA = X + (size_t)(m0 + rowA) * 1024 + cA * 8;
  const unsigned short* srcB = Wt + (size_t)nB * 1024 + cB * 8;

  float4 a0, a1; uint4 breg[6];
  // prologue: load + stage ks=0
  a0 = *(const float4*)(srcA);
  a1 = *(const float4*)(srcA + 4);
  #pragma unroll
  for (int r = 0; r < 6; ++r)
    breg[r] = *(const uint4*)(srcB + (size_t)r * 32 * 1024);
  {
    uint4 p; p.x = pk2(a0.x, a0.y); p.y = pk2(a0.z, a0.w);
    p.z = pk2(a1.x, a1.y); p.w = pk2(a1.z, a1.w);
    *(uint4*)(&As[0][rowA * 72 + cA * 8]) = p;
    #pragma unroll
    for (int r = 0; r < 6; ++r)
      *(uint4*)(&Bs[0][(nB + 32 * r) * 72 + cB * 8]) = breg[r];
  }

  #pragma unroll 2
  for (int ks = 0; ks < 16; ++ks) {
    int cur = ks & 1;
    float4 na0, na1; uint4 nb[6];
    if (ks < 15) {                               // issue ks+1 loads NOW
      const float* sA = srcA + (ks + 1) * 64;
      na0 = *(const float4*)(sA);
      na1 = *(const float4*)(sA + 4);
      const unsigned short* sB = srcB + (ks + 1) * 64;
      #pragma unroll
      for (int r = 0; r < 6; ++r)
        nb[r] = *(const uint4*)(sB + (size_t)r * 32 * 1024);
    }
    __syncthreads();                             // publish buf[cur]
    #pragma unroll
    for (int kk = 0; kk < 64; kk += 32) {
      int ko = kk + quad * 8;
      bf16x8 a = *(const bf16x8*)(&As[cur][(mg * 16 + col) * 72 + ko]);
      #pragma unroll
      for (int ns = 0; ns < 6; ++ns) {
        bf16x8 b = *(const bf16x8*)(&Bs[cur][((ng * 6 + ns) * 16 + col) * 72 + ko]);
        acc[ns] = __builtin_amdgcn_mfma_f32_16x16x32_bf16(a, b, acc[ns], 0, 0, 0);
      }
    }
    if (ks < 15) {                               // consume prefetch -> buf[cur^1]
      uint4 p; p.x = pk2(na0.x, na0.y); p.y = pk2(na0.z, na0.w);
      p.z = pk2(na1.x, na1.y); p.w = pk2(na1.z, na1.w);
      *(uint4*)(&As[cur ^ 1][rowA * 72 + cA * 8]) = p;
      #pragma unroll
      for (int r = 0; r < 6; ++r)
        *(uint4*)(&Bs[cur ^ 1][(nB + 32 * r) * 72 + cB * 8]) = nb[r];
    }
  }
  #pragma unroll
  for (int ns = 0; ns < 6; ++ns)
    #pragma unroll
    for (int r = 0; r < 4; ++r) {
      int m = m0 + mg * 16 + quad * 4 + r;
      int n = ng * 96 + ns * 16 + col;
      qkv[(size_t)m * 192 + n] = acc[ns][r] + bqkv[n];
    }
}

// ---------------- kernel 2: banded flash attention (MFMA) ----------------
// Exact: out-of-band exp underflows to 0; padding mask softmax-invariant.
__global__ __launch_bounds__(256) void band_attn(
    const float* __restrict__ qkv, const float* __restrict__ bias,
    unsigned short* __restrict__ attnout)
{
  __shared__ __align__(16) unsigned short Kl[192 * 72];
  __shared__ __align__(16) unsigned short Vt[64 * 216];
  __shared__ __align__(16) unsigned short Ps[4 * 16 * 168];
  __shared__ float biasL[129];

  int t = threadIdx.x;
  int lane = t & 63, w = t >> 6;
  int col = lane & 15, quad = lane >> 4;
  int bidx = blockIdx.x;
  int b = bidx >> 5;                 // batch
  int i0 = (bidx & 31) * 64;         // first q row (batch coords)
  int jw = i0 - 64;                  // window start (may be <0)
  const float* qbase = qkv + (size_t)(b << 11) * 192;

  if (t < 129) biasL[t] = bias[1984 + t];
  #pragma unroll
  for (int it = 0; it < 24; ++it) {
    int row = it * 8 + (t >> 5);           // 0..191 window row
    int colq = (t & 31) * 4;               // 0..124
    int jb = jw + row;
    int jc = jb < 0 ? 0 : (jb > 2047 ? 2047 : jb);
    const float* src = qbase + (size_t)jc * 192 + 64 + colq;
    float4 f = *(const float4*)src;
    if (colq < 64) {
      *(uint2*)(Kl + row * 72 + colq) = make_uint2(pk2(f.x, f.y), pk2(f.z, f.w));
    } else {
      int p0 = colq - 64;
      Vt[(p0 + 0) * 216 + row] = f2bf(f.x);
      Vt[(p0 + 1) * 216 + row] = f2bf(f.y);
      Vt[(p0 + 2) * 216 + row] = f2bf(f.z);
      Vt[(p0 + 3) * 216 + row] = f2bf(f.w);
    }
  }
  { // zero-fill Vt j-cols 192..207 (PV k-chunk overhang)
    int p = t >> 2, c0 = 192 + (t & 3) * 4;
    *(uint2*)(Vt + p * 216 + c0) = make_uint2(0u, 0u);
  }
  __syncthreads();

  int iq = i0 + w * 16;                    // wave's first q row (batch coords)
  bf16x8 aq0, aq1;
  {
    const float* qr = qbase + (size_t)(iq + col) * 192 + quad * 8;
    float4 f0 = *(const float4*)(qr);
    float4 f1 = *(const float4*)(qr + 4);
    float4 f2 = *(const float4*)(qr + 32);
    float4 f3 = *(const float4*)(qr + 36);
    union { bf16x8 v; uint4 u; } c0_, c1_;
    c0_.u = make_uint4(pk2(f0.x, f0.y), pk2(f0.z, f0.w), pk2(f1.x, f1.y), pk2(f1.z, f1.w));
    c1_.u = make_uint4(pk2(f2.x, f2.y), pk2(f2.z, f2.w), pk2(f3.x, f3.y), pk2(f3.z, f3.w));
    aq0 = c0_.v; aq1 = c1_.v;
  }
  // QK^T: 9 j-tiles
  f32x4 s[9];
  #pragma unroll
  for (int t9 = 0; t9 < 9; ++t9) {
    int krow = ((w + t9) * 16 + col) * 72;
    bf16x8 kb0 = *(const bf16x8*)(Kl + krow + quad * 8);
    bf16x8 kb1 = *(const bf16x8*)(Kl + krow + 32 + quad * 8);
    f32x4 z = {};
    z = __builtin_amdgcn_mfma_f32_16x16x32_bf16(aq0, kb0, z, 0, 0, 0);
    s[t9] = __builtin_amdgcn_mfma_f32_16x16x32_bf16(aq1, kb1, z, 0, 0, 0);
  }
  // mask + bias; row max
  int q4 = quad * 4;
  float mrow[4] = {-3e38f, -3e38f, -3e38f, -3e38f};
  #pragma unroll
  for (int t9 = 0; t9 < 9; ++t9) {
    int j = iq - 64 + t9 * 16 + col;       // batch coords
    #pragma unroll
    for (int r = 0; r < 4; ++r) {
      int diff = q4 + r + 64 - t9 * 16 - col;   // i - j
      bool valid = (j >= 0) & (j < 2048) & (diff >= -64) & (diff <= 64);
      int bi = 64 - diff; bi = bi < 0 ? 0 : (bi > 128 ? 128 : bi);
      float sv = valid ? (s[t9][r] * 0.125f + biasL[bi]) : -3e38f;
      s[t9][r] = sv;
      mrow[r] = fmaxf(mrow[r], sv);
    }
  }
  #pragma unroll
  for (int r = 0; r < 4; ++r) ROW16_MAX(mrow[r]);
  unsigned short* Pw = Ps + w * (16 * 168);
  float lsum[4] = {0.f, 0.f, 0.f, 0.f};
  #pragma unroll
  for (int t9 = 0; t9 < 9; ++t9)
    #pragma unroll
    for (int r = 0; r < 4; ++r) {
      float p = __expf(s[t9][r] - mrow[r]);
      lsum[r] += p;
      Pw[(q4 + r) * 168 + t9 * 16 + col] = f2bf(p);
    }
  #pragma unroll
  for (int r = 0; r < 4; ++r) {
    ROW16_SUM(lsum[r]);
    Pw[(q4 + r) * 168 + 144 + col] = 0;    // zero-pad k-cols 144..159
  }
  // PV: O[16 q][64 p] = P(16x160) . V(160x64)
  f32x4 o[4] = {};
  #pragma unroll
  for (int kc = 0; kc < 5; ++kc) {
    bf16x8 pa = *(const bf16x8*)(Pw + col * 168 + kc * 32 + quad * 8);
    #pragma unroll
    for (int nt = 0; nt < 4; ++nt) {
      bf16x8 vb = *(const bf16x8*)(Vt + (nt * 16 + col) * 216 + 16 * w + kc * 32 + quad * 8);
      o[nt] = __builtin_amdgcn_mfma_f32_16x16x32_bf16(pa, vb, o[nt], 0, 0, 0);
    }
  }
  float rl[4];
  #pragma unroll
  for (int r = 0; r < 4; ++r) rl[r] = 1.0f / lsum[r];
  #pragma unroll
  for (int nt = 0; nt < 4; ++nt)
    #pragma unroll
    for (int r = 0; r < 4; ++r) {
      int arow = (b << 11) + iq + q4 + r;
      attnout[(size_t)arow * 64 + nt * 16 + col] = f2bf(o[nt][r] * rl[r]);
    }
}

// ---------------- kernel 3: output projection (bf16 MFMA) + bias ----------------
__global__ __launch_bounds__(256) void out_gemm(
    const unsigned short* __restrict__ attn, const unsigned short* __restrict__ Wot,
    const float* __restrict__ bo, float* __restrict__ out)
{
  __shared__ __align__(16) unsigned short As[64 * 72];
  __shared__ __align__(16) unsigned short Bs[128 * 72];
  int t = threadIdx.x, lane = t & 63, w = t >> 6;
  int m0 = (blockIdx.x >> 3) * 64;
  int n0 = (blockIdx.x & 7) * 128;
  #pragma unroll
  for (int r = 0; r < 2; ++r) {            // stage A: 64x64 bf16
    int tau = t + 256 * r; int row = tau >> 3, c = tau & 7;
    *(uint4*)(As + row * 72 + c * 8) =
        *(const uint4*)(attn + (size_t)(m0 + row) * 64 + c * 8);
  }
  #pragma unroll
  for (int r = 0; r < 4; ++r) {            // stage B: 128x64 bf16
    int tau = t + 256 * r; int n = tau >> 3, c = tau & 7;
    *(uint4*)(Bs + n * 72 + c * 8) =
        *(const uint4*)(Wot + (size_t)(n0 + n) * 64 + c * 8);
  }
  __syncthreads();
  f32x4 acc[2][4] = {};
  int mg = w & 1, ngg = w >> 1;
  #pragma unroll
  for (int kk = 0; kk < 64; kk += 32) {
    int ko = kk + (lane >> 4) * 8;
    bf16x8 a0 = *(const bf16x8*)(As + (mg * 32 +      (lane & 15)) * 72 + ko);
    bf16x8 a1 = *(const bf16x8*)(As + (mg * 32 + 16 + (lane & 15)) * 72 + ko);
    #pragma unroll
    for (int ns = 0; ns < 4; ++ns) {
      bf16x8 b = *(const bf16x8*)(Bs + ((ngg * 4 + ns) * 16 + (lane & 15)) * 72 + ko);
      acc[0][ns] = __builtin_amdgcn_mfma_f32_16x16x32_bf16(a0, b, acc[0][ns], 0, 0, 0);
      acc[1][ns] = __builtin_amdgcn_mfma_f32_16x16x32_bf16(a1, b, acc[1][ns], 0, 0, 0);
    }
  }
  int col = lane & 15, q = lane >> 4;
  #pragma unroll
  for (int ms = 0; ms < 2; ++ms)
    #pragma unroll
    for (int ns = 0; ns < 4; ++ns)
      #pragma unroll
      for (int r = 0; r < 4; ++r) {
        int mm = m0 + mg * 32 + ms * 16 + q * 4 + r;
        int nn = n0 + (ngg * 4 + ns) * 16 + col;
        out[(size_t)mm * 1024 + nn] = acc[ms][ns][r] + bo[nn];
      }
}

// ---------------- launch ----------------
extern "C" void kernel_launch(void* const* d_in, const int* in_sizes, int n_in,
                              void* d_out, int out_size, void* d_ws, size_t ws_size,
                              hipStream_t stream) {
  const float* X    = (const float*)d_in[0];
  // d_in[1] = attention_mask: per-row constant shift -> softmax-invariant, unused
  const float* Wq   = (const float*)d_in[2];
  const float* bq   = (const float*)d_in[3];
  const float* Wk   = (const float*)d_in[4];
  const float* bk   = (const float*)d_in[5];
  const float* Wv   = (const float*)d_in[6];
  const float* bv   = (const float*)d_in[7];
  const float* Wo   = (const float*)d_in[8];
  const float* bo   = (const float*)d_in[9];
  const float* bias = (const float*)d_in[10];
  float* out = (float*)d_out;
  char* ws = (char*)d_ws;
  float*          qkv  = (float*)(ws);                       // 12,582,912 B
  unsigned short* attn = (unsigned short*)(ws + 12582912);   //  2,097,152 B
  unsigned short* Wt   = (unsigned short*)(ws + 14680064);   //    393,216 B
  unsigned short* Wot  = (unsigned short*)(ws + 15073280);   //    131,072 B
  float*          bqkv = (float*)(ws + 15204352);            //        768 B

  prep_kernel<<<1025, 256, 0, stream>>>(Wq, Wk, Wv, Wo, bq, bk, bv, Wt, Wot, bqkv);
  qkv_gemm<<<512, 256, 0, stream>>>(X, Wt, bqkv, qkv);
  band_attn<<<256, 256, 0, stream>>>(qkv, bias, attn);
  out_gemm<<<2048, 256, 0, stream>>>(attn, Wot, bo, out);
}

// Round 4
// 176.545 us; speedup vs baseline: 1.1893x; 1.1893x over previous
//
#include <hip/hip_runtime.h>

// ---------------- types / helpers ----------------
using bf16x8 = __attribute__((ext_vector_type(8))) short;
using f32x4  = __attribute__((ext_vector_type(4))) float;

static __device__ inline unsigned short f2bf(float f) {
  unsigned int u = __float_as_uint(f);
  u += 0x7fffu + ((u >> 16) & 1u);          // round-to-nearest-even
  return (unsigned short)(u >> 16);
}
static __device__ inline unsigned int pk2(float a, float b) {
  return (unsigned int)f2bf(a) | ((unsigned int)f2bf(b) << 16);
}

// butterfly reductions across the 16-lane DPP row (row_ror 1,2,4,8)
#define ROW16_MAX(x) { \
  { int _t = __builtin_amdgcn_update_dpp(0, __float_as_int(x), 0x121, 0xf, 0xf, true); x = fmaxf(x, __int_as_float(_t)); } \
  { int _t = __builtin_amdgcn_update_dpp(0, __float_as_int(x), 0x122, 0xf, 0xf, true); x = fmaxf(x, __int_as_float(_t)); } \
  { int _t = __builtin_amdgcn_update_dpp(0, __float_as_int(x), 0x124, 0xf, 0xf, true); x = fmaxf(x, __int_as_float(_t)); } \
  { int _t = __builtin_amdgcn_update_dpp(0, __float_as_int(x), 0x128, 0xf, 0xf, true); x = fmaxf(x, __int_as_float(_t)); } }
#define ROW16_SUM(x) { \
  { int _t = __builtin_amdgcn_update_dpp(0, __float_as_int(x), 0x121, 0xf, 0xf, true); x += __int_as_float(_t); } \
  { int _t = __builtin_amdgcn_update_dpp(0, __float_as_int(x), 0x122, 0xf, 0xf, true); x += __int_as_float(_t); } \
  { int _t = __builtin_amdgcn_update_dpp(0, __float_as_int(x), 0x124, 0xf, 0xf, true); x += __int_as_float(_t); } \
  { int _t = __builtin_amdgcn_update_dpp(0, __float_as_int(x), 0x128, 0xf, 0xf, true); x += __int_as_float(_t); } }

// ---------------- kernel 0: weight prep (transpose -> bf16) ----------------
__global__ __launch_bounds__(256) void prep_kernel(
    const float* __restrict__ Wq, const float* __restrict__ Wk, const float* __restrict__ Wv,
    const float* __restrict__ Wo, const float* __restrict__ bq, const float* __restrict__ bk,
    const float* __restrict__ bv,
    unsigned short* __restrict__ Wt, unsigned short* __restrict__ Wot, float* __restrict__ bqkv)
{
  int idx = blockIdx.x * 256 + threadIdx.x;
  if (idx < 192 * 1024) {
    int n = idx >> 10, k = idx & 1023;
    const float* W = (n < 64) ? Wq : (n < 128) ? Wk : Wv;
    Wt[idx] = f2bf(W[k * 64 + (n & 63)]);
  } else if (idx < 192 * 1024 + 1024 * 64) {
    int j = idx - 192 * 1024;
    int n = j >> 6, k = j & 63;
    Wot[j] = f2bf(Wo[k * 1024 + n]);
  } else if (idx < 192 * 1024 + 1024 * 64 + 192) {
    int n = idx - (192 * 1024 + 1024 * 64);
    bqkv[n] = (n < 64) ? bq[n] : (n < 128) ? bk[n - 64] : bv[n - 128];
  }
}

// ---------------- kernel 1: QKV projection (bf16 MFMA) ----------------
// X [16384][1024] fp32, Wt [192][1024] bf16 -> qkv [16384][192] fp32
// BM=32, BN=96 (N split in 2), BK=64; grid 1024 -> 4 blocks/CU = 16 waves/CU.
// Simple 2-barrier body (no reg prefetch: R3 showed it spills -> scratch traffic).
__global__ __launch_bounds__(256) void qkv_gemm(
    const float* __restrict__ X, const unsigned short* __restrict__ Wt,
    const float* __restrict__ bqkv, float* __restrict__ qkv)
{
  __shared__ __align__(16) unsigned short As[32 * 72];
  __shared__ __align__(16) unsigned short Bs[96 * 72];
  int t = threadIdx.x;
  int lane = t & 63, w = t >> 6;
  int m0 = (blockIdx.x >> 1) * 32;
  int nbase = (blockIdx.x & 1) * 96;
  int mg = w & 1, ng = w >> 1;               // wave: 16 rows x 48 cols
  int col = lane & 15, quad = lane >> 4;
  f32x4 acc[3] = {};

  int rowA = t >> 3, cA = t & 7;
  const float* srcA = X + (size_t)(m0 + rowA) * 1024 + cA * 8;
  const unsigned short* srcB = Wt + (size_t)(nbase + rowA) * 1024 + cA * 8;

  for (int ks = 0; ks < 16; ++ks) {
    __syncthreads();
    { // stage A: 32 rows x 64 k, fp32 -> bf16
      const float* s = srcA + ks * 64;
      float4 f0 = *(const float4*)(s);
      float4 f1 = *(const float4*)(s + 4);
      uint4 p;
      p.x = pk2(f0.x, f0.y); p.y = pk2(f0.z, f0.w);
      p.z = pk2(f1.x, f1.y); p.w = pk2(f1.z, f1.w);
      *(uint4*)(As + rowA * 72 + cA * 8) = p;
    }
    #pragma unroll
    for (int r = 0; r < 3; ++r) { // stage B: 96 rows x 64 k (bf16 copy)
      *(uint4*)(Bs + (rowA + 32 * r) * 72 + cA * 8) =
          *(const uint4*)(srcB + (size_t)(32 * r) * 1024 + ks * 64);
    }
    __syncthreads();
    #pragma unroll
    for (int kk = 0; kk < 64; kk += 32) {
      int ko = kk + quad * 8;
      bf16x8 a = *(const bf16x8*)(As + (mg * 16 + col) * 72 + ko);
      #pragma unroll
      for (int ns = 0; ns < 3; ++ns) {
        bf16x8 b = *(const bf16x8*)(Bs + ((ng * 3 + ns) * 16 + col) * 72 + ko);
        acc[ns] = __builtin_amdgcn_mfma_f32_16x16x32_bf16(a, b, acc[ns], 0, 0, 0);
      }
    }
  }
  #pragma unroll
  for (int ns = 0; ns < 3; ++ns)
    #pragma unroll
    for (int r = 0; r < 4; ++r) {
      int m = m0 + mg * 16 + quad * 4 + r;
      int n = nbase + ng * 48 + ns * 16 + col;
      qkv[(size_t)m * 192 + n] = acc[ns][r] + bqkv[n];
    }
}

// ---------------- kernel 2: banded flash attention (MFMA) ----------------
// Exact: out-of-band exp underflows to 0; padding mask softmax-invariant.
__global__ __launch_bounds__(256) void band_attn(
    const float* __restrict__ qkv, const float* __restrict__ bias,
    unsigned short* __restrict__ attnout)
{
  __shared__ __align__(16) unsigned short Kl[192 * 72];
  __shared__ __align__(16) unsigned short Vt[64 * 216];
  __shared__ __align__(16) unsigned short Ps[4 * 16 * 168];
  __shared__ float biasL[129];

  int t = threadIdx.x;
  int lane = t & 63, w = t >> 6;
  int col = lane & 15, quad = lane >> 4;
  int bidx = blockIdx.x;
  int b = bidx >> 5;                 // batch
  int i0 = (bidx & 31) * 64;         // first q row (batch coords)
  int jw = i0 - 64;                  // window start (may be <0)
  const float* qbase = qkv + (size_t)(b << 11) * 192;

  if (t < 129) biasL[t] = bias[1984 + t];
  #pragma unroll
  for (int it = 0; it < 24; ++it) {
    int row = it * 8 + (t >> 5);           // 0..191 window row
    int colq = (t & 31) * 4;               // 0..124
    int jb = jw + row;
    int jc = jb < 0 ? 0 : (jb > 2047 ? 2047 : jb);
    const float* src = qbase + (size_t)jc * 192 + 64 + colq;
    float4 f = *(const float4*)src;
    if (colq < 64) {
      *(uint2*)(Kl + row * 72 + colq) = make_uint2(pk2(f.x, f.y), pk2(f.z, f.w));
    } else {
      int p0 = colq - 64;
      Vt[(p0 + 0) * 216 + row] = f2bf(f.x);
      Vt[(p0 + 1) * 216 + row] = f2bf(f.y);
      Vt[(p0 + 2) * 216 + row] = f2bf(f.z);
      Vt[(p0 + 3) * 216 + row] = f2bf(f.w);
    }
  }
  { // zero-fill Vt j-cols 192..207 (PV k-chunk overhang)
    int p = t >> 2, c0 = 192 + (t & 3) * 4;
    *(uint2*)(Vt + p * 216 + c0) = make_uint2(0u, 0u);
  }
  __syncthreads();

  int iq = i0 + w * 16;                    // wave's first q row (batch coords)
  bf16x8 aq0, aq1;
  {
    const float* qr = qbase + (size_t)(iq + col) * 192 + quad * 8;
    float4 f0 = *(const float4*)(qr);
    float4 f1 = *(const float4*)(qr + 4);
    float4 f2 = *(const float4*)(qr + 32);
    float4 f3 = *(const float4*)(qr + 36);
    union { bf16x8 v; uint4 u; } c0_, c1_;
    c0_.u = make_uint4(pk2(f0.x, f0.y), pk2(f0.z, f0.w), pk2(f1.x, f1.y), pk2(f1.z, f1.w));
    c1_.u = make_uint4(pk2(f2.x, f2.y), pk2(f2.z, f2.w), pk2(f3.x, f3.y), pk2(f3.z, f3.w));
    aq0 = c0_.v; aq1 = c1_.v;
  }
  // QK^T: 9 j-tiles
  f32x4 s[9];
  #pragma unroll
  for (int t9 = 0; t9 < 9; ++t9) {
    int krow = ((w + t9) * 16 + col) * 72;
    bf16x8 kb0 = *(const bf16x8*)(Kl + krow + quad * 8);
    bf16x8 kb1 = *(const bf16x8*)(Kl + krow + 32 + quad * 8);
    f32x4 z = {};
    z = __builtin_amdgcn_mfma_f32_16x16x32_bf16(aq0, kb0, z, 0, 0, 0);
    s[t9] = __builtin_amdgcn_mfma_f32_16x16x32_bf16(aq1, kb1, z, 0, 0, 0);
  }
  // mask + bias; row max
  int q4 = quad * 4;
  float mrow[4] = {-3e38f, -3e38f, -3e38f, -3e38f};
  #pragma unroll
  for (int t9 = 0; t9 < 9; ++t9) {
    int j = iq - 64 + t9 * 16 + col;       // batch coords
    #pragma unroll
    for (int r = 0; r < 4; ++r) {
      int diff = q4 + r + 64 - t9 * 16 - col;   // i - j
      bool valid = (j >= 0) & (j < 2048) & (diff >= -64) & (diff <= 64);
      int bi = 64 - diff; bi = bi < 0 ? 0 : (bi > 128 ? 128 : bi);
      float sv = valid ? (s[t9][r] * 0.125f + biasL[bi]) : -3e38f;
      s[t9][r] = sv;
      mrow[r] = fmaxf(mrow[r], sv);
    }
  }
  #pragma unroll
  for (int r = 0; r < 4; ++r) ROW16_MAX(mrow[r]);
  unsigned short* Pw = Ps + w * (16 * 168);
  float lsum[4] = {0.f, 0.f, 0.f, 0.f};
  #pragma unroll
  for (int t9 = 0; t9 < 9; ++t9)
    #pragma unroll
    for (int r = 0; r < 4; ++r) {
      float p = __expf(s[t9][r] - mrow[r]);
      lsum[r] += p;
      Pw[(q4 + r) * 168 + t9 * 16 + col] = f2bf(p);
    }
  #pragma unroll
  for (int r = 0; r < 4; ++r) {
    ROW16_SUM(lsum[r]);
    Pw[(q4 + r) * 168 + 144 + col] = 0;    // zero-pad k-cols 144..159
  }
  // PV: O[16 q][64 p] = P(16x160) . V(160x64)
  f32x4 o[4] = {};
  #pragma unroll
  for (int kc = 0; kc < 5; ++kc) {
    bf16x8 pa = *(const bf16x8*)(Pw + col * 168 + kc * 32 + quad * 8);
    #pragma unroll
    for (int nt = 0; nt < 4; ++nt) {
      bf16x8 vb = *(const bf16x8*)(Vt + (nt * 16 + col) * 216 + 16 * w + kc * 32 + quad * 8);
      o[nt] = __builtin_amdgcn_mfma_f32_16x16x32_bf16(pa, vb, o[nt], 0, 0, 0);
    }
  }
  float rl[4];
  #pragma unroll
  for (int r = 0; r < 4; ++r) rl[r] = 1.0f / lsum[r];
  #pragma unroll
  for (int nt = 0; nt < 4; ++nt)
    #pragma unroll
    for (int r = 0; r < 4; ++r) {
      int arow = (b << 11) + iq + q4 + r;
      attnout[(size_t)arow * 64 + nt * 16 + col] = f2bf(o[nt][r] * rl[r]);
    }
}

// ---------------- kernel 3: output projection (bf16 MFMA) + bias ----------------
__global__ __launch_bounds__(256) void out_gemm(
    const unsigned short* __restrict__ attn, const unsigned short* __restrict__ Wot,
    const float* __restrict__ bo, float* __restrict__ out)
{
  __shared__ __align__(16) unsigned short As[64 * 72];
  __shared__ __align__(16) unsigned short Bs[128 * 72];
  int t = threadIdx.x, lane = t & 63, w = t >> 6;
  int m0 = (blockIdx.x >> 3) * 64;
  int n0 = (blockIdx.x & 7) * 128;
  #pragma unroll
  for (int r = 0; r < 2; ++r) {            // stage A: 64x64 bf16
    int tau = t + 256 * r; int row = tau >> 3, c = tau & 7;
    *(uint4*)(As + row * 72 + c * 8) =
        *(const uint4*)(attn + (size_t)(m0 + row) * 64 + c * 8);
  }
  #pragma unroll
  for (int r = 0; r < 4; ++r) {            // stage B: 128x64 bf16
    int tau = t + 256 * r; int n = tau >> 3, c = tau & 7;
    *(uint4*)(Bs + n * 72 + c * 8) =
        *(const uint4*)(Wot + (size_t)(n0 + n) * 64 + c * 8);
  }
  __syncthreads();
  f32x4 acc[2][4] = {};
  int mg = w & 1, ngg = w >> 1;
  #pragma unroll
  for (int kk = 0; kk < 64; kk += 32) {
    int ko = kk + (lane >> 4) * 8;
    bf16x8 a0 = *(const bf16x8*)(As + (mg * 32 +      (lane & 15)) * 72 + ko);
    bf16x8 a1 = *(const bf16x8*)(As + (mg * 32 + 16 + (lane & 15)) * 72 + ko);
    #pragma unroll
    for (int ns = 0; ns < 4; ++ns) {
      bf16x8 b = *(const bf16x8*)(Bs + ((ngg * 4 + ns) * 16 + (lane & 15)) * 72 + ko);
      acc[0][ns] = __builtin_amdgcn_mfma_f32_16x16x32_bf16(a0, b, acc[0][ns], 0, 0, 0);
      acc[1][ns] = __builtin_amdgcn_mfma_f32_16x16x32_bf16(a1, b, acc[1][ns], 0, 0, 0);
    }
  }
  int col = lane & 15, q = lane >> 4;
  #pragma unroll
  for (int ms = 0; ms < 2; ++ms)
    #pragma unroll
    for (int ns = 0; ns < 4; ++ns)
      #pragma unroll
      for (int r = 0; r < 4; ++r) {
        int mm = m0 + mg * 32 + ms * 16 + q * 4 + r;
        int nn = n0 + (ngg * 4 + ns) * 16 + col;
        out[(size_t)mm * 1024 + nn] = acc[ms][ns][r] + bo[nn];
      }
}

// ---------------- launch ----------------
extern "C" void kernel_launch(void* const* d_in, const int* in_sizes, int n_in,
                              void* d_out, int out_size, void* d_ws, size_t ws_size,
                              hipStream_t stream) {
  const float* X    = (const float*)d_in[0];
  // d_in[1] = attention_mask: per-row constant shift -> softmax-invariant, unused
  const float* Wq   = (const float*)d_in[2];
  const float* bq   = (const float*)d_in[3];
  const float* Wk   = (const float*)d_in[4];
  const float* bk   = (const float*)d_in[5];
  const float* Wv   = (const float*)d_in[6];
  const float* bv   = (const float*)d_in[7];
  const float* Wo   = (const float*)d_in[8];
  const float* bo   = (const float*)d_in[9];
  const float* bias = (const float*)d_in[10];
  float* out = (float*)d_out;
  char* ws = (char*)d_ws;
  float*          qkv  = (float*)(ws);                       // 12,582,912 B
  unsigned short* attn = (unsigned short*)(ws + 12582912);   //  2,097,152 B
  unsigned short* Wt   = (unsigned short*)(ws + 14680064);   //    393,216 B
  unsigned short* Wot  = (unsigned short*)(ws + 15073280);   //    131,072 B
  float*          bqkv = (float*)(ws + 15204352);            //        768 B

  prep_kernel<<<1025, 256, 0, stream>>>(Wq, Wk, Wv, Wo, bq, bk, bv, Wt, Wot, bqkv);
  qkv_gemm<<<1024, 256, 0, stream>>>(X, Wt, bqkv, qkv);
  band_attn<<<256, 256, 0, stream>>>(qkv, bias, attn);
  out_gemm<<<2048, 256, 0, stream>>>(attn, Wot, bo, out);
}